// Round 1
// baseline (807.632 us; speedup 1.0000x reference)
//
#include <hip/hip_runtime.h>
#include <hip/hip_bf16.h>
#include <stdint.h>

// Problem constants: x[8192,4096] f32, qw[4096,4096] f32 in {-1,+1}, bias[4096]
#define B_DIM   8192
#define IN_DIM  4096
#define OUT_DIM 4096
#define QB_V    128.0f
#define EPS_V   1e-5f
// out-group: 512 rows  = 2^21 elems ; batch-group: 1024 rows = 2^22 elems

typedef __attribute__((ext_vector_type(4))) float  f32x4;
typedef __attribute__((ext_vector_type(8))) __bf16 bf16x8;
typedef __attribute__((ext_vector_type(4))) __bf16 bf16x4;

__device__ __forceinline__ void gload_lds16(const void* g, void* l) {
  void* gp = const_cast<void*>(g);
  __builtin_amdgcn_global_load_lds(
      (__attribute__((address_space(1))) void*)gp,
      (__attribute__((address_space(3))) void*)l, 16, 0, 0);
}

__device__ __forceinline__ __bf16 sgnb(float d) {
  return (__bf16)((d > 0.f) ? 1.f : (d < 0.f ? -1.f : 0.f));
}

// ---- zero the 16-word scratch header (sums[8] f32 + gamma_bits[8] u32) ----
__global__ void k_init(unsigned* ws) {
  int t = threadIdx.x;
  if (t < 16) ws[t] = 0u;
}

// ---- per-out-group sum of |qw| (integers -> exact f32 atomics) ----
__global__ __launch_bounds__(256) void k_qw_sums(const float* __restrict__ qw,
                                                 float* __restrict__ sums) {
  __shared__ float red[4];
  const int t = threadIdx.x;
  const size_t base = (size_t)blockIdx.x * 4096;
  float s = 0.f;
#pragma unroll
  for (int j = 0; j < 4; ++j) {
    f32x4 v = *(const f32x4*)(qw + base + (size_t)j * 1024 + t * 4);
    s += fabsf(v.x) + fabsf(v.y) + fabsf(v.z) + fabsf(v.w);
  }
#pragma unroll
  for (int off = 32; off > 0; off >>= 1) s += __shfl_xor(s, off);
  if ((t & 63) == 0) red[t >> 6] = s;
  __syncthreads();
  if (t == 0) {
    float bs = red[0] + red[1] + red[2] + red[3];
    atomicAdd(sums + (blockIdx.x >> 9), bs);  // 512 blocks per group
  }
}

// ---- bw = sign(qw - mu_g) as bf16 ----
__global__ __launch_bounds__(256) void k_conv_bw(const float* __restrict__ qw,
                                                 const float* __restrict__ sums,
                                                 __bf16* __restrict__ bw) {
  const size_t i = ((size_t)blockIdx.x * 256 + threadIdx.x) * 4;
  const int g = (int)(i >> 21);
  const float mu = sums[g] * (1.0f / 2097152.0f);  // / (512*4096)
  f32x4 v = *(const f32x4*)(qw + i);
  bf16x4 r;
  r.x = sgnb(v.x - mu);
  r.y = sgnb(v.y - mu);
  r.z = sgnb(v.z - mu);
  r.w = sgnb(v.w - mu);
  *(bf16x4*)(bw + i) = r;
}

// ---- x -> bf16 ----
__global__ __launch_bounds__(256) void k_conv_x(const float* __restrict__ x,
                                                __bf16* __restrict__ xb) {
  const size_t i = ((size_t)blockIdx.x * 256 + threadIdx.x) * 4;
  f32x4 v = *(const f32x4*)(x + i);
  bf16x4 r;
  r.x = (__bf16)v.x; r.y = (__bf16)v.y; r.z = (__bf16)v.z; r.w = (__bf16)v.w;
  *(bf16x4*)(xb + i) = r;
}

// ---- GEMM: out[b,o] = sum_k x[b,k]*bw[o,k] + bias[o]; fused group-|max| ----
// 128x128 tile, BK=64, 256 thr = 4 waves (2x2), 64x64/wave, 16x16x32 bf16 MFMA.
// AMODE 0: A,B pre-converted bf16 via global_load_lds (needs 96MB ws)
// AMODE 1: A reg-staged from f32 x; B pre-converted (needs 32MB ws)
// AMODE 2: A and B reg-staged from f32 (ws header only)
template <int AMODE>
__global__ __launch_bounds__(256) void k_gemm(
    const __bf16* __restrict__ xa, const float* __restrict__ xf,
    const __bf16* __restrict__ bwb, const float* __restrict__ qw,
    const float* __restrict__ sums, const float* __restrict__ bias,
    float* __restrict__ out, unsigned* __restrict__ gamma_bits) {
  __shared__ __bf16 As[128 * 64];
  __shared__ __bf16 Bs[128 * 64];
  const int t = threadIdx.x;
  const int lane = t & 63;
  const int wv = t >> 6;
  const int wr = wv >> 1, wc = wv & 1;
  const int fr = lane & 15, fq = lane >> 4;
  const int bid = blockIdx.x;
  const int bm = bid & 63, bn = bid >> 6;
  const int brow = bm << 7, bcol = bn << 7;

  f32x4 acc[4][4] = {};

  // staging chunk: c = it*256 + t ; row = c>>3 ; col = (c&7)*8
  const int c0row = t >> 3;          // +32 per it
  const int ccol = (t & 7) << 3;

  float muB = 0.f;
  if (AMODE == 2) muB = sums[bcol >> 9] * (1.0f / 2097152.0f);

  for (int kt = 0; kt < IN_DIM / 64; ++kt) {
    const int k0 = kt << 6;
    if (AMODE == 0) {
      __syncthreads();
#pragma unroll
      for (int it = 0; it < 4; ++it) {
        const int row = c0row + it * 32;
        gload_lds16(xa + (size_t)(brow + row) * IN_DIM + k0 + ccol,
                    As + (row << 6) + ccol);
        gload_lds16(bwb + (size_t)(bcol + row) * IN_DIM + k0 + ccol,
                    Bs + (row << 6) + ccol);
      }
      __syncthreads();
    } else if (AMODE == 1) {
      f32x4 a0[4], a1[4];
#pragma unroll
      for (int it = 0; it < 4; ++it) {
        const int row = c0row + it * 32;
        const float* p = xf + (size_t)(brow + row) * IN_DIM + k0 + ccol;
        a0[it] = *(const f32x4*)p;
        a1[it] = *(const f32x4*)(p + 4);
      }
      __syncthreads();
#pragma unroll
      for (int it = 0; it < 4; ++it) {
        const int row = c0row + it * 32;
        gload_lds16(bwb + (size_t)(bcol + row) * IN_DIM + k0 + ccol,
                    Bs + (row << 6) + ccol);
      }
#pragma unroll
      for (int it = 0; it < 4; ++it) {
        const int row = c0row + it * 32;
        bf16x8 w;
        w[0] = (__bf16)a0[it].x; w[1] = (__bf16)a0[it].y;
        w[2] = (__bf16)a0[it].z; w[3] = (__bf16)a0[it].w;
        w[4] = (__bf16)a1[it].x; w[5] = (__bf16)a1[it].y;
        w[6] = (__bf16)a1[it].z; w[7] = (__bf16)a1[it].w;
        *(bf16x8*)(As + (row << 6) + ccol) = w;
      }
      __syncthreads();
    } else {
      f32x4 a0[4], a1[4], b0[4], b1[4];
#pragma unroll
      for (int it = 0; it < 4; ++it) {
        const int row = c0row + it * 32;
        const float* pa = xf + (size_t)(brow + row) * IN_DIM + k0 + ccol;
        a0[it] = *(const f32x4*)pa;
        a1[it] = *(const f32x4*)(pa + 4);
        const float* pb = qw + (size_t)(bcol + row) * IN_DIM + k0 + ccol;
        b0[it] = *(const f32x4*)pb;
        b1[it] = *(const f32x4*)(pb + 4);
      }
      __syncthreads();
#pragma unroll
      for (int it = 0; it < 4; ++it) {
        const int row = c0row + it * 32;
        bf16x8 wa, wb;
        wa[0] = (__bf16)a0[it].x; wa[1] = (__bf16)a0[it].y;
        wa[2] = (__bf16)a0[it].z; wa[3] = (__bf16)a0[it].w;
        wa[4] = (__bf16)a1[it].x; wa[5] = (__bf16)a1[it].y;
        wa[6] = (__bf16)a1[it].z; wa[7] = (__bf16)a1[it].w;
        wb[0] = sgnb(b0[it].x - muB); wb[1] = sgnb(b0[it].y - muB);
        wb[2] = sgnb(b0[it].z - muB); wb[3] = sgnb(b0[it].w - muB);
        wb[4] = sgnb(b1[it].x - muB); wb[5] = sgnb(b1[it].y - muB);
        wb[6] = sgnb(b1[it].z - muB); wb[7] = sgnb(b1[it].w - muB);
        *(bf16x8*)(As + (row << 6) + ccol) = wa;
        *(bf16x8*)(Bs + (row << 6) + ccol) = wb;
      }
      __syncthreads();
    }

    // 2 K-steps of 32 -> 32 MFMAs per barrier pair
#pragma unroll
    for (int ks = 0; ks < 2; ++ks) {
      bf16x8 af[4], bfr[4];
#pragma unroll
      for (int mi = 0; mi < 4; ++mi)
        af[mi] = *(const bf16x8*)(As + ((wr << 6) + (mi << 4) + fr) * 64 +
                                  (ks << 5) + (fq << 3));
#pragma unroll
      for (int ni = 0; ni < 4; ++ni)
        bfr[ni] = *(const bf16x8*)(Bs + ((wc << 6) + (ni << 4) + fr) * 64 +
                                   (ks << 5) + (fq << 3));
#pragma unroll
      for (int mi = 0; mi < 4; ++mi)
#pragma unroll
        for (int ni = 0; ni < 4; ++ni)
          acc[mi][ni] = __builtin_amdgcn_mfma_f32_16x16x32_bf16(
              af[mi], bfr[ni], acc[mi][ni], 0, 0, 0);
    }
  }

  // epilogue: +bias, store f32, fused per-batch-group abs-max
  float mx = 0.f;
  const int colbase = bcol + (wc << 6);
#pragma unroll
  for (int ni = 0; ni < 4; ++ni) {
    const int col = colbase + (ni << 4) + fr;
    const float bv = bias[col];
#pragma unroll
    for (int mi = 0; mi < 4; ++mi) {
      const int rowb = brow + (wr << 6) + (mi << 4) + (fq << 2);
#pragma unroll
      for (int j = 0; j < 4; ++j) {
        const float v = acc[mi][ni][j] + bv;
        out[(size_t)(rowb + j) * OUT_DIM + col] = v;
        mx = fmaxf(mx, fabsf(v));
      }
    }
  }
#pragma unroll
  for (int off = 32; off > 0; off >>= 1) mx = fmaxf(mx, __shfl_xor(mx, off));
  if (lane == 0)
    atomicMax(gamma_bits + (brow >> 10), __float_as_uint(mx));
}

// ---- q = clip(out * 128/(gamma_g+eps), -128+eps, 128-eps), in place ----
__global__ __launch_bounds__(256) void k_scale(float* __restrict__ out,
                                               const unsigned* __restrict__ gb) {
  const size_t i = ((size_t)blockIdx.x * 256 + threadIdx.x) * 4;
  const int g = (int)(i >> 22);
  const float gamma = __uint_as_float(gb[g]);
  const float sc = QB_V / (gamma + EPS_V);
  const float lo = -QB_V + EPS_V, hi = QB_V - EPS_V;
  f32x4 v = *(const f32x4*)(out + i);
  v.x = fminf(fmaxf(v.x * sc, lo), hi);
  v.y = fminf(fmaxf(v.y * sc, lo), hi);
  v.z = fminf(fmaxf(v.z * sc, lo), hi);
  v.w = fminf(fmaxf(v.w * sc, lo), hi);
  *(f32x4*)(out + i) = v;
}

extern "C" void kernel_launch(void* const* d_in, const int* in_sizes, int n_in,
                              void* d_out, int out_size, void* d_ws,
                              size_t ws_size, hipStream_t stream) {
  const float* x = (const float*)d_in[0];
  const float* qw = (const float*)d_in[1];
  const float* bias = (const float*)d_in[2];
  float* out = (float*)d_out;
  char* ws = (char*)d_ws;
  float* sums = (float*)ws;                   // 8 x f32
  unsigned* gamma = (unsigned*)ws + 8;        // 8 x u32 (f32 bits, >=0)
  __bf16* bwb = (__bf16*)(ws + 256);
  __bf16* xb = (__bf16*)(ws + 256 + (size_t)OUT_DIM * IN_DIM * 2);

  const size_t need1 = 256 + (size_t)OUT_DIM * IN_DIM * 2;                 // 32MB
  const size_t need0 = need1 + (size_t)B_DIM * IN_DIM * 2;                 // +64MB
  const int amode = (ws_size >= need0) ? 0 : ((ws_size >= need1) ? 1 : 2);

  k_init<<<1, 64, 0, stream>>>((unsigned*)ws);
  k_qw_sums<<<4096, 256, 0, stream>>>(qw, sums);
  if (amode <= 1) k_conv_bw<<<16384, 256, 0, stream>>>(qw, sums, bwb);
  if (amode == 0) k_conv_x<<<32768, 256, 0, stream>>>(x, xb);

  if (amode == 0)
    k_gemm<0><<<2048, 256, 0, stream>>>(xb, x, bwb, qw, sums, bias, out, gamma);
  else if (amode == 1)
    k_gemm<1><<<2048, 256, 0, stream>>>(xb, x, bwb, qw, sums, bias, out, gamma);
  else
    k_gemm<2><<<2048, 256, 0, stream>>>(xb, x, bwb, qw, sums, bias, out, gamma);

  k_scale<<<32768, 256, 0, stream>>>(out, gamma);
}